// Round 6
// baseline (366.113 us; speedup 1.0000x reference)
//
#include <hip/hip_runtime.h>

#define S_Q 512
#define DIM 512
#define SCALE_F 0.04419417382415922f  // 1/sqrt(512)
#define LDS_W 520                     // LDS row stride in shorts (breaks pow2 aliasing)
#define CF_W 516                      // fp32 LDS stride (breaks 4-row bank alias)

typedef short short8 __attribute__((ext_vector_type(8)));
typedef float floatx4 __attribute__((ext_vector_type(4)));

__device__ __forceinline__ float wave_sum(float v) {
#pragma unroll
  for (int o = 32; o > 0; o >>= 1) v += __shfl_xor(v, o);
  return v;
}
__device__ __forceinline__ unsigned short f2bf(float f) {
  unsigned u = __float_as_uint(f);
  return (unsigned short)((u + 0x7FFFu + ((u >> 16) & 1u)) >> 16);
}
__device__ __forceinline__ float bf2f(short s) {
  return __uint_as_float(((unsigned)(unsigned short)s) << 16);
}

// async global->LDS, 16B per lane (dest = wave-uniform base + lane*16).
__device__ __forceinline__ void gload16(const void* g, void* l) {
  __builtin_amdgcn_global_load_lds(
      (const __attribute__((address_space(1))) unsigned int*)g,
      (__attribute__((address_space(3))) unsigned int*)l, 16, 0, 0);
}

// ---------------------------------------------------------------------------
// K1: cross-attention partials (round-5 version, unchanged). 5 structural
// variants all pinned at 53-60us with every pipe <25% busy — suspended;
// the tail is the bigger, never-directly-profiled cost.
// ---------------------------------------------------------------------------
__global__ __launch_bounds__(256) void k_ca_partial(
    const float* __restrict__ tgt, const float* __restrict__ qpos,
    const float* __restrict__ mem, const float* __restrict__ pos,
    unsigned short* __restrict__ part_acc, float* __restrict__ part_ms) {
  const int j = blockIdx.x;
  const int tid = threadIdx.x;
  const int w = tid >> 6, lane = tid & 63;
  __shared__ short q_hi[4][LDS_W];
  __shared__ short q_lo[4][LDS_W];
  __shared__ float stage_mem[4][2][16 * 32];
  __shared__ float stage_pos[4][2][16 * 32];
  __shared__ float p_lds[4][3][16];
  __shared__ float wacc[4][3][DIM];
  __shared__ float wms[4][3][2];

  {
    const int d0 = lane * 8;
    const int qi = j - 1 + w;
    if (w < 3 && (unsigned)qi < (unsigned)S_Q) {
      float4 t0 = *(const float4*)(tgt + (size_t)qi * DIM + d0);
      float4 t1 = *(const float4*)(tgt + (size_t)qi * DIM + d0 + 4);
      float4 q0 = *(const float4*)(qpos + (size_t)qi * DIM + d0);
      float4 q1 = *(const float4*)(qpos + (size_t)qi * DIM + d0 + 4);
      float v[8] = {t0.x + q0.x, t0.y + q0.y, t0.z + q0.z, t0.w + q0.w,
                    t1.x + q1.x, t1.y + q1.y, t1.z + q1.z, t1.w + q1.w};
      short8 hi, lo;
#pragma unroll
      for (int e = 0; e < 8; ++e) {
        unsigned short h = f2bf(v[e]);
        hi[e] = (short)h;
        lo[e] = (short)f2bf(v[e] - bf2f((short)h));
      }
      *(short8*)(&q_hi[w][d0]) = hi;
      *(short8*)(&q_lo[w][d0]) = lo;
    } else {
      short8 z = {0, 0, 0, 0, 0, 0, 0, 0};
      *(short8*)(&q_hi[w][d0]) = z;
      *(short8*)(&q_lo[w][d0]) = z;
    }
  }
  __syncthreads();

  const int arow = lane & 15;
  const int kgrp = lane >> 4;
  const int qrow = (arow < 3) ? arow : 3;
  const float* mrow = mem + ((size_t)j * 64 + w * 16) * DIM;
  const float* prow = pos + ((size_t)j * 64 + w * 16) * DIM;
  const int sfrm = lane >> 3;
  const int sorg = (((lane & 7) ^ (lane >> 3)) << 4);

#define CA_ISSUE(KC, BUF)                                                    \
  do {                                                                       \
    const char* gm = (const char*)(mrow + (size_t)sfrm * DIM) + (KC)*128 + sorg; \
    const char* gp = (const char*)(prow + (size_t)sfrm * DIM) + (KC)*128 + sorg; \
    gload16(gm, (void*)&stage_mem[w][BUF][0]);                               \
    gload16(gm + 8 * DIM * 4, (void*)&stage_mem[w][BUF][256]);               \
    gload16(gp, (void*)&stage_pos[w][BUF][0]);                               \
    gload16(gp + 8 * DIM * 4, (void*)&stage_pos[w][BUF][256]);               \
  } while (0)

  CA_ISSUE(0, 0);

  floatx4 acc_hh = {0.f, 0.f, 0.f, 0.f};
  floatx4 acc_lh = {0.f, 0.f, 0.f, 0.f};
  floatx4 acc_hl = {0.f, 0.f, 0.f, 0.f};
  const int sw = (arow & 7) << 4;
  const int rowb = arow * 128;
  const int cA = rowb + (((kgrp * 32) + 0) ^ sw);
  const int cB = rowb + (((kgrp * 32) + 16) ^ sw);

  for (int kc = 0; kc < 16; ++kc) {
    const int cur = kc & 1;
    if (kc < 15) {
      CA_ISSUE(kc + 1, cur ^ 1);
      asm volatile("s_waitcnt vmcnt(4)" ::: "memory");
    } else {
      asm volatile("s_waitcnt vmcnt(0)" ::: "memory");
    }
    const char* smb = (const char*)&stage_mem[w][cur][0];
    const char* spb = (const char*)&stage_pos[w][cur][0];
    const float4 mA = *(const float4*)(smb + cA);
    const float4 mB = *(const float4*)(smb + cB);
    const float4 pA = *(const float4*)(spb + cA);
    const float4 pB = *(const float4*)(spb + cB);
    float kv[8] = {mA.x + pA.x, mA.y + pA.y, mA.z + pA.z, mA.w + pA.w,
                   mB.x + pB.x, mB.y + pB.y, mB.z + pB.z, mB.w + pB.w};
    short8 ah, al;
#pragma unroll
    for (int e = 0; e < 8; ++e) {
      unsigned short h = f2bf(kv[e]);
      ah[e] = (short)h;
      al[e] = (short)f2bf(kv[e] - bf2f((short)h));
    }
    const int qcol = kc * 32 + kgrp * 8;
    const short8 qh = *(const short8*)(&q_hi[qrow][qcol]);
    const short8 ql = *(const short8*)(&q_lo[qrow][qcol]);
    acc_hh = __builtin_amdgcn_mfma_f32_16x16x32_bf16(ah, qh, acc_hh, 0, 0, 0);
    acc_lh = __builtin_amdgcn_mfma_f32_16x16x32_bf16(al, qh, acc_lh, 0, 0, 0);
    acc_hl = __builtin_amdgcn_mfma_f32_16x16x32_bf16(ah, ql, acc_hl, 0, 0, 0);
  }
#undef CA_ISSUE

  float s[4];
#pragma unroll
  for (int r = 0; r < 4; ++r)
    s[r] = (acc_hh[r] + acc_lh[r] + acc_hl[r]) * SCALE_F;
  float mloc = fmaxf(fmaxf(s[0], s[1]), fmaxf(s[2], s[3]));
  mloc = fmaxf(mloc, __shfl_xor(mloc, 16));
  mloc = fmaxf(mloc, __shfl_xor(mloc, 32));
  float p[4], sloc = 0.f;
#pragma unroll
  for (int r = 0; r < 4; ++r) {
    p[r] = __expf(s[r] - mloc);
    sloc += p[r];
  }
  sloc += __shfl_xor(sloc, 16);
  sloc += __shfl_xor(sloc, 32);
  if (arow < 3) {
    *(float4*)(&p_lds[w][arow][kgrp * 4]) = make_float4(p[0], p[1], p[2], p[3]);
    if (lane < 3) {
      wms[w][lane][0] = mloc;
      wms[w][lane][1] = sloc;
    }
  }

  const int d0 = lane * 8;
  float acc[3][8];
#pragma unroll
  for (int c = 0; c < 3; ++c)
#pragma unroll
    for (int e = 0; e < 8; ++e) acc[c][e] = 0.f;
  const float* mb = mem + ((size_t)j * 64 + w * 16) * DIM + d0;
#pragma unroll 4
  for (int f = 0; f < 16; ++f) {
    float4 m0 = *(const float4*)(mb + (size_t)f * DIM);
    float4 m1 = *(const float4*)(mb + (size_t)f * DIM + 4);
    const float mv[8] = {m0.x, m0.y, m0.z, m0.w, m1.x, m1.y, m1.z, m1.w};
    const float w0 = p_lds[w][0][f];
    const float w1 = p_lds[w][1][f];
    const float w2 = p_lds[w][2][f];
#pragma unroll
    for (int e = 0; e < 8; ++e) {
      acc[0][e] += w0 * mv[e];
      acc[1][e] += w1 * mv[e];
      acc[2][e] += w2 * mv[e];
    }
  }

#pragma unroll
  for (int c = 0; c < 3; ++c) {
    *(float4*)(&wacc[w][c][d0]) =
        make_float4(acc[c][0], acc[c][1], acc[c][2], acc[c][3]);
    *(float4*)(&wacc[w][c][d0 + 4]) =
        make_float4(acc[c][4], acc[c][5], acc[c][6], acc[c][7]);
  }
  __syncthreads();

  const int d = tid * 2;
#pragma unroll
  for (int c = 0; c < 3; ++c) {
    const int qi = j - 1 + c;
    if ((unsigned)qi >= (unsigned)S_Q) continue;
    float M = wms[0][c][0];
#pragma unroll
    for (int u = 1; u < 4; ++u) M = fmaxf(M, wms[u][c][0]);
    float S = 0.f, ax = 0.f, ay = 0.f;
#pragma unroll
    for (int u = 0; u < 4; ++u) {
      const float wg = __expf(wms[u][c][0] - M);
      S += wg * wms[u][c][1];
      const float2 a = *(const float2*)(&wacc[u][c][d]);
      ax += wg * a.x;
      ay += wg * a.y;
    }
    const size_t slot = (size_t)qi * 3 + c;
    unsigned* dst = (unsigned*)(part_acc + slot * DIM + d);
    *dst = (unsigned)f2bf(ax) | ((unsigned)f2bf(ay) << 16);
    if (tid == 0) {
      part_ms[slot * 2 + 0] = M;
      part_ms[slot * 2 + 1] = S;
    }
  }
}

// ---------------------------------------------------------------------------
// Shared GEMM pieces.
// ---------------------------------------------------------------------------
__device__ __forceinline__ void stage_tile(const float* __restrict__ G,
                                           short* __restrict__ Ls,
                                           int rowblk, int tid) {
  const int w = tid >> 6, lane = tid & 63;
  const int col = lane * 8;
#pragma unroll
  for (int u = 0; u < 8; ++u) {
    const int row = u * 4 + w;
    const float* src = G + (size_t)(rowblk * 32 + row) * DIM + col;
    float4 a = *(const float4*)src;
    float4 b = *(const float4*)(src + 4);
    short8 s;
    s[0] = (short)f2bf(a.x); s[1] = (short)f2bf(a.y);
    s[2] = (short)f2bf(a.z); s[3] = (short)f2bf(a.w);
    s[4] = (short)f2bf(b.x); s[5] = (short)f2bf(b.y);
    s[6] = (short)f2bf(b.z); s[7] = (short)f2bf(b.w);
    *(short8*)(&Ls[row * LDS_W + col]) = s;
  }
}

__device__ __forceinline__ floatx4 gemm_tile_acc(const short* __restrict__ ap,
                                                 const short* __restrict__ wp) {
  floatx4 acc = {0.f, 0.f, 0.f, 0.f};
#pragma unroll
  for (int kc = 0; kc < 16; ++kc) {
    const short8 af = *(const short8*)(ap + kc * 32);
    const short8 wf = *(const short8*)(wp + kc * 32);
    acc = __builtin_amdgcn_mfma_f32_16x16x32_bf16(af, wf, acc, 0, 0, 0);
  }
  return acc;
}

template <bool RELU>
__device__ __forceinline__ void gemm_core(const short* __restrict__ As,
                                          const short* __restrict__ Ws,
                                          const float* __restrict__ bias,
                                          float* __restrict__ C, int bx, int by,
                                          int wave, int lane) {
  const int r0 = (wave >> 1) * 16, c0 = (wave & 1) * 16;
  const int frow = lane & 15, fk = (lane >> 4) * 8;
  floatx4 acc =
      gemm_tile_acc(&As[(r0 + frow) * LDS_W + fk], &Ws[(c0 + frow) * LDS_W + fk]);
  const int col = bx * 32 + c0 + frow;
  const int rowb = by * 32 + r0 + (lane >> 4) * 4;
  const float b = bias[col];
#pragma unroll
  for (int r = 0; r < 4; ++r) {
    float v = acc[r] + b;
    if (RELU) v = fmaxf(v, 0.f);
    C[(size_t)(rowb + r) * DIM + col] = v;
  }
}

// tile-gemm -> fp32 LDS (stride CF_W), bias added. col = wt*32 + local.
__device__ __forceinline__ void gemm_tile_to_f32lds(
    const short* __restrict__ As, const short* __restrict__ Ws,
    const float* __restrict__ bias, float* __restrict__ Cf, int wt, int wave,
    int lane) {
  const int r0 = (wave >> 1) * 16, c0 = (wave & 1) * 16;
  const int frow = lane & 15, fk = (lane >> 4) * 8;
  floatx4 acc =
      gemm_tile_acc(&As[(r0 + frow) * LDS_W + fk], &Ws[(c0 + frow) * LDS_W + fk]);
  const int col = wt * 32 + c0 + frow;
  const int rowb = r0 + (lane >> 4) * 4;
  const float b = bias[col];
#pragma unroll
  for (int r = 0; r < 4; ++r) Cf[(rowb + r) * CF_W + col] = acc[r] + b;
}

// tile-gemm -> bf16 LDS (stride LDS_W), bias + relu.
__device__ __forceinline__ void gemm_tile_to_bf16lds_relu(
    const short* __restrict__ As, const short* __restrict__ Ws,
    const float* __restrict__ bias, short* __restrict__ Hb, int wt, int wave,
    int lane) {
  const int r0 = (wave >> 1) * 16, c0 = (wave & 1) * 16;
  const int frow = lane & 15, fk = (lane >> 4) * 8;
  floatx4 acc =
      gemm_tile_acc(&As[(r0 + frow) * LDS_W + fk], &Ws[(c0 + frow) * LDS_W + fk]);
  const int col = wt * 32 + c0 + frow;
  const int rowb = r0 + (lane >> 4) * 4;
  const float b = bias[col];
#pragma unroll
  for (int r = 0; r < 4; ++r)
    Hb[(rowb + r) * LDS_W + col] = (short)f2bf(fmaxf(acc[r] + b, 0.f));
}

// LN prologue: As[r] = bf16(LN(X[row]+R[row])*g+b) for 32 rows; optionally
// write fp32 LN result to x_out.
__device__ __forceinline__ void ln_prologue(const float* __restrict__ X,
                                            const float* __restrict__ R,
                                            const float* __restrict__ g,
                                            const float* __restrict__ b,
                                            short* __restrict__ As, int by,
                                            float* x_out, int wave, int lane) {
  const int d0 = lane * 8;
  float gg[8], bb[8];
  {
    float4 g0 = *(const float4*)(g + d0);
    float4 g1 = *(const float4*)(g + d0 + 4);
    float4 b0 = *(const float4*)(b + d0);
    float4 b1 = *(const float4*)(b + d0 + 4);
    gg[0] = g0.x; gg[1] = g0.y; gg[2] = g0.z; gg[3] = g0.w;
    gg[4] = g1.x; gg[5] = g1.y; gg[6] = g1.z; gg[7] = g1.w;
    bb[0] = b0.x; bb[1] = b0.y; bb[2] = b0.z; bb[3] = b0.w;
    bb[4] = b1.x; bb[5] = b1.y; bb[6] = b1.z; bb[7] = b1.w;
  }
  for (int r = wave; r < 32; r += 4) {
    const int grow = by * 32 + r;
    const float* xp = X + (size_t)grow * DIM + d0;
    const float* rp = R + (size_t)grow * DIM + d0;
    float4 x0 = *(const float4*)xp;
    float4 x1 = *(const float4*)(xp + 4);
    float4 r0 = *(const float4*)rp;
    float4 r1 = *(const float4*)(rp + 4);
    float v[8] = {x0.x + r0.x, x0.y + r0.y, x0.z + r0.z, x0.w + r0.w,
                  x1.x + r1.x, x1.y + r1.y, x1.z + r1.z, x1.w + r1.w};
    float s = 0.f, sq = 0.f;
#pragma unroll
    for (int e = 0; e < 8; ++e) { s += v[e]; sq += v[e] * v[e]; }
#pragma unroll
    for (int o = 32; o > 0; o >>= 1) {
      s += __shfl_xor(s, o);
      sq += __shfl_xor(sq, o);
    }
    const float mean = s * (1.f / DIM);
    const float var = sq * (1.f / DIM) - mean * mean;
    const float rstd = rsqrtf(var + 1e-5f);
    float o8[8];
    short8 sv;
#pragma unroll
    for (int e = 0; e < 8; ++e) {
      o8[e] = (v[e] - mean) * rstd * gg[e] + bb[e];
      sv[e] = (short)f2bf(o8[e]);
    }
    *(short8*)(&As[r * LDS_W + d0]) = sv;
    if (x_out) {
      *(float4*)(x_out + (size_t)grow * DIM + d0) =
          make_float4(o8[0], o8[1], o8[2], o8[3]);
      *(float4*)(x_out + (size_t)grow * DIM + d0 + 4) =
          make_float4(o8[4], o8[5], o8[6], o8[7]);
    }
  }
}

// ---------------------------------------------------------------------------
// T1 = G1+G2+G3 fused, block-local (no grid sync). Block (bx,by) owns output
// rows by*32..+32 and f-cols bx*32..+32. It computes t2 and h for its rows
// across ALL 512 cols by streaming the full Wt2l and W1 (2 MB from L2,
// shared by all blocks -> HBM once), keeping t2 fp32 / h bf16 entirely in
// LDS. Rationale: tail kernels averaged ~33us each (7 kernels ~231us) vs
// ~5-10us intrinsic work -> per-kernel boundary cost dominates; fusion cuts
// 3 boundaries and removes t2/h global round-trips.
// LDS: As 33.3K + Ws 33.3K + T2f 66K = 132.6K (1 block/CU; grid=256=1/CU).
// ---------------------------------------------------------------------------
__global__ __launch_bounds__(256) void k_t1(
    const unsigned short* __restrict__ part_acc,
    const float* __restrict__ part_ms, const float* __restrict__ tgt,
    const float* __restrict__ Wt2l, const float* __restrict__ bt2l,
    const float* __restrict__ W1, const float* __restrict__ b1,
    const float* __restrict__ W2, const float* __restrict__ b2,
    const float* __restrict__ n2g, const float* __restrict__ n2b,
    float* __restrict__ x_out, float* __restrict__ f_out) {
  __shared__ short As[32 * LDS_W];
  __shared__ short Ws[32 * LDS_W];
  __shared__ float T2f[32 * CF_W];
  short* Hb = (short*)T2f;  // overlay: T2f dead once h-loop writes begin
  const int tid = threadIdx.x;
  const int bx = blockIdx.x, by = blockIdx.y;
  const int wave = tid >> 6, lane = tid & 63;
  const int d0 = lane * 8;

  // ---- 1) combine partials (finish softmax) + relu -> As (bf16)
  for (int r = wave; r < 32; r += 4) {
    const int i = by * 32 + r;
    const bool valid[3] = {i < S_Q - 1, true, i > 0};
    float mm[3], ss[3], M = -1e30f;
#pragma unroll
    for (int c = 0; c < 3; ++c) {
      if (valid[c]) {
        mm[c] = part_ms[((size_t)i * 3 + c) * 2 + 0];
        ss[c] = part_ms[((size_t)i * 3 + c) * 2 + 1];
        M = fmaxf(M, mm[c]);
      } else {
        mm[c] = -1e30f;
        ss[c] = 0.f;
      }
    }
    float den = 0.f, wg[3];
#pragma unroll
    for (int c = 0; c < 3; ++c) {
      wg[c] = valid[c] ? __expf(mm[c] - M) : 0.f;
      den += wg[c] * ss[c];
    }
    const float inv = 1.f / den;
    float o[8] = {0.f, 0.f, 0.f, 0.f, 0.f, 0.f, 0.f, 0.f};
#pragma unroll
    for (int c = 0; c < 3; ++c) {
      if (valid[c]) {
        const short8 pa =
            *(const short8*)(part_acc + ((size_t)i * 3 + c) * DIM + d0);
#pragma unroll
        for (int e = 0; e < 8; ++e) o[e] += wg[c] * bf2f(pa[e]);
      }
    }
    short8 sv;
#pragma unroll
    for (int e = 0; e < 8; ++e) sv[e] = (short)f2bf(fmaxf(o[e] * inv, 0.f));
    *(short8*)(&As[r * LDS_W + d0]) = sv;
  }

  // ---- 2) t2 (own rows, ALL cols): 16 tiles of Wt2l -> T2f fp32.
  for (int wt = 0; wt < 16; ++wt) {
    __syncthreads();  // As ready (wt=0) / Ws free (wt>0)
    stage_tile(Wt2l, Ws, wt, tid);
    __syncthreads();
    gemm_tile_to_f32lds(As, Ws, bt2l, T2f, wt, wave, lane);
  }
  __syncthreads();  // T2f complete; As free

  // ---- 3) x = LN(tgt + t2) -> As bf16 (+ fp32 x_out when bx==0)
  {
    float gg[8], bb[8];
    float4 g0 = *(const float4*)(n2g + d0);
    float4 g1 = *(const float4*)(n2g + d0 + 4);
    float4 b0 = *(const float4*)(n2b + d0);
    float4 b1 = *(const float4*)(n2b + d0 + 4);
    gg[0] = g0.x; gg[1] = g0.y; gg[2] = g0.z; gg[3] = g0.w;
    gg[4] = g1.x; gg[5] = g1.y; gg[6] = g1.z; gg[7] = g1.w;
    bb[0] = b0.x; bb[1] = b0.y; bb[2] = b0.z; bb[3] = b0.w;
    bb[4] = b1.x; bb[5] = b1.y; bb[6] = b1.z; bb[7] = b1.w;
    for (int r = wave; r < 32; r += 4) {
      const int grow = by * 32 + r;
      const float* tp = tgt + (size_t)grow * DIM + d0;
      float4 t0 = *(const float4*)tp;
      float4 t1 = *(const float4*)(tp + 4);
      const float* trow = &T2f[r * CF_W + d0];
      float v[8] = {t0.x + trow[0], t0.y + trow[1], t0.z + trow[2],
                    t0.w + trow[3], t1.x + trow[4], t1.y + trow[5],
                    t1.z + trow[6], t1.w + trow[7]};
      float s = 0.f, sq = 0.f;
#pragma unroll
      for (int e = 0; e < 8; ++e) { s += v[e]; sq += v[e] * v[e]; }
#pragma unroll
      for (int o = 32; o > 0; o >>= 1) {
        s += __shfl_xor(s, o);
        sq += __shfl_xor(sq, o);
      }
      const float mean = s * (1.f / DIM);
      const float var = sq * (1.f / DIM) - mean * mean;
      const float rstd = rsqrtf(var + 1e-5f);
      float o8[8];
      short8 sv;
#pragma unroll
      for (int e = 0; e < 8; ++e) {
        o8[e] = (v[e] - mean) * rstd * gg[e] + bb[e];
        sv[e] = (short)f2bf(o8[e]);
      }
      *(short8*)(&As[r * LDS_W + d0]) = sv;
      if (bx == 0) {
        *(float4*)(x_out + (size_t)grow * DIM + d0) =
            make_float4(o8[0], o8[1], o8[2], o8[3]);
        *(float4*)(x_out + (size_t)grow * DIM + d0 + 4) =
            make_float4(o8[4], o8[5], o8[6], o8[7]);
      }
    }
  }

  // ---- 4) h = relu(x @ W1^T + b1) (own rows, ALL cols) -> Hb bf16.
  for (int wt = 0; wt < 16; ++wt) {
    __syncthreads();  // LN done (wt=0: protects T2f->Hb overlay) / Ws free
    stage_tile(W1, Ws, wt, tid);
    __syncthreads();
    gemm_tile_to_bf16lds_relu(As, Ws, b1, Hb, wt, wave, lane);
  }

  // ---- 5) f tile (own rows, own cols) = h @ W2^T + b2 -> global.
  __syncthreads();
  stage_tile(W2, Ws, bx, tid);
  __syncthreads();
  gemm_core<false>(Hb, Ws, b2, f_out, bx, by, wave, lane);
}

// ---------------------------------------------------------------------------
// G4: x2 = LN(x+f) on a 40-row window (write own rows when bx==0), banded
// self-attention (+/-4) + ReLU -> GEMM with sa_conv_w. (Unchanged; its ±4-row
// window is cross-block, so it stays a separate kernel.)
// ---------------------------------------------------------------------------
__global__ __launch_bounds__(256) void k_g4(
    const float* __restrict__ X, const float* __restrict__ R,
    const float* __restrict__ g, const float* __restrict__ b,
    const float* __restrict__ W, const float* __restrict__ bias,
    float* __restrict__ C, float* __restrict__ x2_out) {
  __shared__ short Xw[40 * LDS_W];
  __shared__ short As[32 * LDS_W];
  __shared__ short Ws[32 * LDS_W];
  const int tid = threadIdx.x;
  const int bx = blockIdx.x, by = blockIdx.y;
  const int wave = tid >> 6, lane = tid & 63;
  const int d0 = lane * 8;
  const int wlo = (by * 32 - 4 > 0) ? by * 32 - 4 : 0;
  const int whi = (by * 32 + 35 < S_Q - 1) ? by * 32 + 35 : S_Q - 1;
  const int nw = whi - wlo + 1;

  {
    float gg[8], bb[8];
    float4 g0 = *(const float4*)(g + d0);
    float4 g1 = *(const float4*)(g + d0 + 4);
    float4 b0 = *(const float4*)(b + d0);
    float4 b1 = *(const float4*)(b + d0 + 4);
    gg[0] = g0.x; gg[1] = g0.y; gg[2] = g0.z; gg[3] = g0.w;
    gg[4] = g1.x; gg[5] = g1.y; gg[6] = g1.z; gg[7] = g1.w;
    bb[0] = b0.x; bb[1] = b0.y; bb[2] = b0.z; bb[3] = b0.w;
    bb[4] = b1.x; bb[5] = b1.y; bb[6] = b1.z; bb[7] = b1.w;
    for (int r = wave; r < nw; r += 4) {
      const int grow = wlo + r;
      const float* xp = X + (size_t)grow * DIM + d0;
      const float* rp = R + (size_t)grow * DIM + d0;
      float4 x0 = *(const float4*)xp;
      float4 x1 = *(const float4*)(xp + 4);
      float4 r0 = *(const float4*)rp;
      float4 r1 = *(const float4*)(rp + 4);
      float v[8] = {x0.x + r0.x, x0.y + r0.y, x0.z + r0.z, x0.w + r0.w,
                    x1.x + r1.x, x1.y + r1.y, x1.z + r1.z, x1.w + r1.w};
      float s = 0.f, sq = 0.f;
#pragma unroll
      for (int e = 0; e < 8; ++e) { s += v[e]; sq += v[e] * v[e]; }
#pragma unroll
      for (int o = 32; o > 0; o >>= 1) {
        s += __shfl_xor(s, o);
        sq += __shfl_xor(sq, o);
      }
      const float mean = s * (1.f / DIM);
      const float var = sq * (1.f / DIM) - mean * mean;
      const float rstd = rsqrtf(var + 1e-5f);
      float o8[8];
      short8 sv;
#pragma unroll
      for (int e = 0; e < 8; ++e) {
        o8[e] = (v[e] - mean) * rstd * gg[e] + bb[e];
        sv[e] = (short)f2bf(o8[e]);
      }
      *(short8*)(&Xw[r * LDS_W + d0]) = sv;
      if (bx == 0 && grow >= by * 32 && grow < by * 32 + 32) {
        *(float4*)(x2_out + (size_t)grow * DIM + d0) =
            make_float4(o8[0], o8[1], o8[2], o8[3]);
        *(float4*)(x2_out + (size_t)grow * DIM + d0 + 4) =
            make_float4(o8[4], o8[5], o8[6], o8[7]);
      }
    }
  }
  stage_tile(W, Ws, bx, tid);
  __syncthreads();

  for (int li = wave; li < 32; li += 4) {
    const int i = by * 32 + li;
    const int lq = i - wlo;
    float qv[8];
    {
      const short8 qs = *(const short8*)(&Xw[lq * LDS_W + d0]);
#pragma unroll
      for (int e = 0; e < 8; ++e) qv[e] = bf2f(qs[e]);
    }
    const int jlo = (i - 4 > 0) ? i - 4 : 0;
    const int jhi = (i + 4 < S_Q - 1) ? i + 4 : S_Q - 1;
    const int n = jhi - jlo + 1;
    float sc[9];
#pragma unroll
    for (int k = 0; k < 9; ++k) {
      if (k < n) {
        const int lk = jlo + k - wlo;
        const short8 ks = *(const short8*)(&Xw[lk * LDS_W + d0]);
        float dd = 0.f;
#pragma unroll
        for (int e = 0; e < 8; ++e) dd += qv[e] * bf2f(ks[e]);
        sc[k] = dd;
      } else {
        sc[k] = 0.f;
      }
    }
#pragma unroll
    for (int o = 32; o > 0; o >>= 1)
#pragma unroll
      for (int k = 0; k < 9; ++k) sc[k] += __shfl_xor(sc[k], o);
    float M = -1e30f;
#pragma unroll
    for (int k = 0; k < 9; ++k) {
      sc[k] *= SCALE_F;
      if (k < n) M = fmaxf(M, sc[k]);
    }
    float p[9], den = 0.f;
#pragma unroll
    for (int k = 0; k < 9; ++k) {
      p[k] = (k < n) ? __expf(sc[k] - M) : 0.f;
      den += p[k];
    }
    const float inv = 1.f / den;
    float o8[8] = {0.f, 0.f, 0.f, 0.f, 0.f, 0.f, 0.f, 0.f};
#pragma unroll
    for (int k = 0; k < 9; ++k) {
      if (k < n) {
        const int lk = jlo + k - wlo;
        const short8 ks = *(const short8*)(&Xw[lk * LDS_W + d0]);
#pragma unroll
        for (int e = 0; e < 8; ++e) o8[e] += p[k] * bf2f(ks[e]);
      }
    }
    short8 sv;
#pragma unroll
    for (int e = 0; e < 8; ++e) sv[e] = (short)f2bf(fmaxf(o8[e] * inv, 0.f));
    *(short8*)(&As[li * LDS_W + d0]) = sv;
  }
  __syncthreads();
  gemm_core<false>(As, Ws, bias, C, bx, by, wave, lane);
}

// ---------------------------------------------------------------------------
// T2 = G5+G6 fused: y1 = LN(x2+c) (fp32 out when bx==0) -> h2 full-row via
// 16 sa_l1 tiles (bf16 LDS, no global round-trip) -> f2 tile -> global.
// LDS: As + Ws + Hb2 = 100 KB.
// ---------------------------------------------------------------------------
__global__ __launch_bounds__(256) void k_t2(
    const float* __restrict__ x2, const float* __restrict__ c,
    const float* __restrict__ n1g, const float* __restrict__ n1b,
    const float* __restrict__ Wl1, const float* __restrict__ bl1,
    const float* __restrict__ Wl2, const float* __restrict__ bl2,
    float* __restrict__ y1_out, float* __restrict__ f2_out) {
  __shared__ short As[32 * LDS_W];
  __shared__ short Ws[32 * LDS_W];
  __shared__ short Hb2[32 * LDS_W];
  const int tid = threadIdx.x;
  const int bx = blockIdx.x, by = blockIdx.y;
  const int wave = tid >> 6, lane = tid & 63;

  ln_prologue(x2, c, n1g, n1b, As, by, (bx == 0) ? y1_out : nullptr, wave, lane);

  for (int wt = 0; wt < 16; ++wt) {
    __syncthreads();  // As ready (wt=0) / Ws free
    stage_tile(Wl1, Ws, wt, tid);
    __syncthreads();
    gemm_tile_to_bf16lds_relu(As, Ws, bl1, Hb2, wt, wave, lane);
  }

  __syncthreads();
  stage_tile(Wl2, Ws, bx, tid);
  __syncthreads();
  gemm_core<false>(Hb2, Ws, bl2, f2_out, bx, by, wave, lane);
}

// ---------------------------------------------------------------------------
// Final: out = LN(y1 + f2).
// ---------------------------------------------------------------------------
__global__ __launch_bounds__(256) void k_addln(
    const float* __restrict__ X, const float* __restrict__ R,
    const float* __restrict__ g, const float* __restrict__ b,
    float* __restrict__ out) {
  const int row = blockIdx.x * 4 + (threadIdx.x >> 6);
  const int lane = threadIdx.x & 63;
  const int d = lane * 8;
  const float4* xp = (const float4*)(X + (size_t)row * DIM + d);
  const float4* rp = (const float4*)(R + (size_t)row * DIM + d);
  float4 x0 = xp[0], x1 = xp[1], r0 = rp[0], r1 = rp[1];
  float v[8] = {x0.x + r0.x, x0.y + r0.y, x0.z + r0.z, x0.w + r0.w,
                x1.x + r1.x, x1.y + r1.y, x1.z + r1.z, x1.w + r1.w};
  float s = 0.f, sq = 0.f;
#pragma unroll
  for (int e = 0; e < 8; ++e) { s += v[e]; sq += v[e] * v[e]; }
  s = wave_sum(s);
  sq = wave_sum(sq);
  const float mean = s * (1.f / DIM);
  const float var = sq * (1.f / DIM) - mean * mean;
  const float rstd = rsqrtf(var + 1e-5f);
  const float4* gp = (const float4*)(g + d);
  const float4* bp = (const float4*)(b + d);
  float4 g0 = gp[0], g1 = gp[1], bb0 = bp[0], bb1 = bp[1];
  float4 o0, o1;
  o0.x = (v[0] - mean) * rstd * g0.x + bb0.x;
  o0.y = (v[1] - mean) * rstd * g0.y + bb0.y;
  o0.z = (v[2] - mean) * rstd * g0.z + bb0.z;
  o0.w = (v[3] - mean) * rstd * g0.w + bb0.w;
  o1.x = (v[4] - mean) * rstd * g1.x + bb1.x;
  o1.y = (v[5] - mean) * rstd * g1.y + bb1.y;
  o1.z = (v[6] - mean) * rstd * g1.z + bb1.z;
  o1.w = (v[7] - mean) * rstd * g1.w + bb1.w;
  *(float4*)(out + (size_t)row * DIM + d) = o0;
  *(float4*)(out + (size_t)row * DIM + d + 4) = o1;
}

// ---------------------------------------------------------------------------
extern "C" void kernel_launch(void* const* d_in, const int* in_sizes, int n_in,
                              void* d_out, int out_size, void* d_ws, size_t ws_size,
                              hipStream_t stream) {
  const float* tgt       = (const float*)d_in[0];
  const float* memory    = (const float*)d_in[1];
  const float* pos       = (const float*)d_in[2];
  const float* qpos      = (const float*)d_in[3];
  // d_in[4] action_idx: analytically t/64, unused
  const float* ca_t2l_w  = (const float*)d_in[5];
  const float* ca_t2l_b  = (const float*)d_in[6];
  const float* ca_l1_w   = (const float*)d_in[7];
  const float* ca_l1_b   = (const float*)d_in[8];
  const float* ca_l2_w   = (const float*)d_in[9];
  const float* ca_l2_b   = (const float*)d_in[10];
  const float* ca_n2_g   = (const float*)d_in[11];
  const float* ca_n2_b   = (const float*)d_in[12];
  const float* ca_n3_g   = (const float*)d_in[13];
  const float* ca_n3_b   = (const float*)d_in[14];
  const float* sa_conv_w = (const float*)d_in[15];
  const float* sa_conv_b = (const float*)d_in[16];
  const float* sa_l1_w   = (const float*)d_in[17];
  const float* sa_l1_b   = (const float*)d_in[18];
  const float* sa_l2_w   = (const float*)d_in[19];
  const float* sa_l2_b   = (const float*)d_in[20];
  const float* sa_n1_g   = (const float*)d_in[21];
  const float* sa_n1_b   = (const float*)d_in[22];
  const float* sa_n2_g   = (const float*)d_in[23];
  const float* sa_n2_b   = (const float*)d_in[24];
  float* out = (float*)d_out;
  float* ws = (float*)d_ws;

  // workspace (floats), aliased by lifetime; peak 1182720 floats = 4.73 MB
  // (same as prior rounds).
  //   part: [ca, T1)    @ 0      (396288: acc 393216 + ms 6144)
  //   x:    [T1, G4)    @ 396288
  //   f:    [T1, G4)    @ 658432
  //   c:    [G4, T2)    @ 0        (part dead)
  //   x2:   [G4, T2)    @ 920576
  //   y1:   [T2, addln) @ 396288   (x dead)
  //   f2:   [T2, addln) @ 658432   (f dead)
  unsigned short* part_acc = (unsigned short*)ws;
  float* part_ms = ws + 393216;
  float* x  = ws + 396288;
  float* f  = ws + 658432;
  float* c  = ws + 0;
  float* x2 = ws + 920576;
  float* y1 = ws + 396288;
  float* f2 = ws + 658432;

  const dim3 gg(16, 16, 1);

  k_ca_partial<<<512, 256, 0, stream>>>(tgt, qpos, memory, pos, part_acc, part_ms);
  k_t1<<<gg, 256, 0, stream>>>(part_acc, part_ms, tgt, ca_t2l_w, ca_t2l_b,
                               ca_l1_w, ca_l1_b, ca_l2_w, ca_l2_b, ca_n2_g,
                               ca_n2_b, x, f);
  k_g4<<<gg, 256, 0, stream>>>(x, f, ca_n3_g, ca_n3_b, sa_conv_w, sa_conv_b, c, x2);
  k_t2<<<gg, 256, 0, stream>>>(x2, c, sa_n1_g, sa_n1_b, sa_l1_w, sa_l1_b,
                               sa_l2_w, sa_l2_b, y1, f2);
  k_addln<<<128, 256, 0, stream>>>(f2, y1, sa_n2_g, sa_n2_b, out);
}

// Round 7
// 284.522 us; speedup vs baseline: 1.2868x; 1.2868x over previous
//
#include <hip/hip_runtime.h>

#define S_Q 512
#define DIM 512
#define SCALE_F 0.04419417382415922f  // 1/sqrt(512)
#define LDS_W 520                     // LDS row stride in shorts (breaks pow2 aliasing)

typedef short short8 __attribute__((ext_vector_type(8)));
typedef float floatx4 __attribute__((ext_vector_type(4)));

__device__ __forceinline__ float wave_sum(float v) {
#pragma unroll
  for (int o = 32; o > 0; o >>= 1) v += __shfl_xor(v, o);
  return v;
}
__device__ __forceinline__ unsigned short f2bf(float f) {
  unsigned u = __float_as_uint(f);
  return (unsigned short)((u + 0x7FFFu + ((u >> 16) & 1u)) >> 16);
}
__device__ __forceinline__ float bf2f(short s) {
  return __uint_as_float(((unsigned)(unsigned short)s) << 16);
}

// ---------------------------------------------------------------------------
// K1: cross-attention partials. One block per 64-frame segment j; queries
// j-1,j,j+1. Wave handles 16 frames in 4 batches of 4. (Empirical optimum:
// rounds 1-6 falsified occupancy-doubling, block-splitting, MFMA-scores,
// gload_lds pipelining, coop-grid fusion, and block-local fusion — all
// landed at 53-60us for this kernel / >=287us total. This 4-wave PV-in-
// register version measured 53.9us, total 279.6us.)
// ---------------------------------------------------------------------------
__global__ __launch_bounds__(256) void k_ca_partial(
    const float* __restrict__ tgt, const float* __restrict__ qpos,
    const float* __restrict__ mem, const float* __restrict__ pos,
    unsigned short* __restrict__ part_acc, float* __restrict__ part_ms) {
  const int j = blockIdx.x;
  const int tid = threadIdx.x;
  const int wave = tid >> 6, lane = tid & 63;
  const int d0 = lane * 8;
  __shared__ float wacc[4][3][DIM];
  __shared__ float wms[4][3][2];

  float qf[3][8];
#pragma unroll
  for (int c = 0; c < 3; ++c) {
    const int qi = j - 1 + c;
    if ((unsigned)qi < (unsigned)S_Q) {
      float4 t0 = *(const float4*)(tgt + (size_t)qi * DIM + d0);
      float4 t1 = *(const float4*)(tgt + (size_t)qi * DIM + d0 + 4);
      float4 q0 = *(const float4*)(qpos + (size_t)qi * DIM + d0);
      float4 q1 = *(const float4*)(qpos + (size_t)qi * DIM + d0 + 4);
      qf[c][0] = t0.x + q0.x; qf[c][1] = t0.y + q0.y;
      qf[c][2] = t0.z + q0.z; qf[c][3] = t0.w + q0.w;
      qf[c][4] = t1.x + q1.x; qf[c][5] = t1.y + q1.y;
      qf[c][6] = t1.z + q1.z; qf[c][7] = t1.w + q1.w;
    } else {
#pragma unroll
      for (int e = 0; e < 8; ++e) qf[c][e] = 0.f;
    }
  }

  float m[3] = {-1e30f, -1e30f, -1e30f};
  float ssum[3] = {0.f, 0.f, 0.f};
  float acc[3][8];
#pragma unroll
  for (int c = 0; c < 3; ++c)
#pragma unroll
    for (int e = 0; e < 8; ++e) acc[c][e] = 0.f;

  const float* mbase = mem + ((size_t)j * 64 + wave * 16) * DIM + d0;
  const float* pbase = pos + ((size_t)j * 64 + wave * 16) * DIM + d0;

  for (int b = 0; b < 4; ++b) {
    float mv[4][8], kk[4][8];
#pragma unroll
    for (int f = 0; f < 4; ++f) {
      const float* mp = mbase + (size_t)(b * 4 + f) * DIM;
      const float* pp = pbase + (size_t)(b * 4 + f) * DIM;
      float4 a = *(const float4*)mp;
      float4 bb = *(const float4*)(mp + 4);
      float4 c4 = *(const float4*)pp;
      float4 dd = *(const float4*)(pp + 4);
      mv[f][0] = a.x;  mv[f][1] = a.y;  mv[f][2] = a.z;  mv[f][3] = a.w;
      mv[f][4] = bb.x; mv[f][5] = bb.y; mv[f][6] = bb.z; mv[f][7] = bb.w;
      kk[f][0] = a.x + c4.x;  kk[f][1] = a.y + c4.y;
      kk[f][2] = a.z + c4.z;  kk[f][3] = a.w + c4.w;
      kk[f][4] = bb.x + dd.x; kk[f][5] = bb.y + dd.y;
      kk[f][6] = bb.z + dd.z; kk[f][7] = bb.w + dd.w;
    }
    float dots[3][4];
#pragma unroll
    for (int f = 0; f < 4; ++f) {
      float s0 = 0.f, s1 = 0.f, s2 = 0.f;
#pragma unroll
      for (int e = 0; e < 8; ++e) {
        s0 += qf[0][e] * kk[f][e];
        s1 += qf[1][e] * kk[f][e];
        s2 += qf[2][e] * kk[f][e];
      }
      dots[0][f] = s0; dots[1][f] = s1; dots[2][f] = s2;
    }
#pragma unroll
    for (int o = 32; o > 0; o >>= 1)
#pragma unroll
      for (int c = 0; c < 3; ++c)
#pragma unroll
        for (int f = 0; f < 4; ++f) dots[c][f] += __shfl_xor(dots[c][f], o);
#pragma unroll
    for (int c = 0; c < 3; ++c) {
      float s[4];
#pragma unroll
      for (int f = 0; f < 4; ++f) s[f] = dots[c][f] * SCALE_F;
      const float bm = fmaxf(fmaxf(s[0], s[1]), fmaxf(s[2], s[3]));
      const float nm = fmaxf(m[c], bm);
      const float fct = __expf(m[c] - nm);
      m[c] = nm;
      ssum[c] *= fct;
#pragma unroll
      for (int e = 0; e < 8; ++e) acc[c][e] *= fct;
#pragma unroll
      for (int f = 0; f < 4; ++f) {
        const float w = __expf(s[f] - nm);
        ssum[c] += w;
#pragma unroll
        for (int e = 0; e < 8; ++e) acc[c][e] += w * mv[f][e];
      }
    }
  }

#pragma unroll
  for (int c = 0; c < 3; ++c) {
    *(float4*)(&wacc[wave][c][d0]) =
        make_float4(acc[c][0], acc[c][1], acc[c][2], acc[c][3]);
    *(float4*)(&wacc[wave][c][d0 + 4]) =
        make_float4(acc[c][4], acc[c][5], acc[c][6], acc[c][7]);
    if (lane == 0) { wms[wave][c][0] = m[c]; wms[wave][c][1] = ssum[c]; }
  }
  __syncthreads();

  const int d = tid * 2;
#pragma unroll
  for (int c = 0; c < 3; ++c) {
    const int qi = j - 1 + c;
    if ((unsigned)qi >= (unsigned)S_Q) continue;
    float M = wms[0][c][0];
#pragma unroll
    for (int w = 1; w < 4; ++w) M = fmaxf(M, wms[w][c][0]);
    float S = 0.f, ax = 0.f, ay = 0.f;
#pragma unroll
    for (int w = 0; w < 4; ++w) {
      const float wg = __expf(wms[w][c][0] - M);
      S += wg * wms[w][c][1];
      const float2 a = *(const float2*)(&wacc[w][c][d]);
      ax += wg * a.x;
      ay += wg * a.y;
    }
    const size_t slot = (size_t)qi * 3 + c;
    unsigned short* dst = part_acc + slot * DIM + d;
    dst[0] = f2bf(ax);
    dst[1] = f2bf(ay);
    if (tid == 0) {
      part_ms[slot * 2 + 0] = M;
      part_ms[slot * 2 + 1] = S;
    }
  }
}

// ---------------------------------------------------------------------------
// Shared GEMM pieces. Tile: 32(M) x 32(N), K=512 fully LDS-resident (bf16).
// stage_tile: WAVE-COALESCED — wave w covers row 4u+w, lane covers 8
// consecutive floats at col lane*8 (adjacent lanes adjacent addresses).
// ---------------------------------------------------------------------------
__device__ __forceinline__ void stage_tile(const float* __restrict__ G,
                                           short* __restrict__ Ls,
                                           int rowblk, int tid) {
  const int w = tid >> 6, lane = tid & 63;
  const int col = lane * 8;
#pragma unroll
  for (int u = 0; u < 8; ++u) {
    const int row = u * 4 + w;
    const float* src = G + (size_t)(rowblk * 32 + row) * DIM + col;
    float4 a = *(const float4*)src;
    float4 b = *(const float4*)(src + 4);
    short8 s;
    s[0] = (short)f2bf(a.x); s[1] = (short)f2bf(a.y);
    s[2] = (short)f2bf(a.z); s[3] = (short)f2bf(a.w);
    s[4] = (short)f2bf(b.x); s[5] = (short)f2bf(b.y);
    s[6] = (short)f2bf(b.z); s[7] = (short)f2bf(b.w);
    *(short8*)(&Ls[row * LDS_W + col]) = s;
  }
}

template <bool RELU>
__device__ __forceinline__ void gemm_core(const short* __restrict__ As,
                                          const short* __restrict__ Ws,
                                          const float* __restrict__ bias,
                                          float* __restrict__ C, int bx, int by,
                                          int wave, int lane) {
  const int r0 = (wave >> 1) * 16, c0 = (wave & 1) * 16;
  const int frow = lane & 15, fk = (lane >> 4) * 8;
  const short* ap = &As[(r0 + frow) * LDS_W + fk];
  const short* wp = &Ws[(c0 + frow) * LDS_W + fk];
  floatx4 acc = {0.f, 0.f, 0.f, 0.f};
#pragma unroll
  for (int kc = 0; kc < 16; ++kc) {
    const short8 af = *(const short8*)(ap + kc * 32);
    const short8 wf = *(const short8*)(wp + kc * 32);
    acc = __builtin_amdgcn_mfma_f32_16x16x32_bf16(af, wf, acc, 0, 0, 0);
  }
  const int col = bx * 32 + c0 + frow;
  const int rowb = by * 32 + r0 + (lane >> 4) * 4;
  const float b = bias[col];
#pragma unroll
  for (int r = 0; r < 4; ++r) {
    float v = acc[r] + b;
    if (RELU) v = fmaxf(v, 0.f);
    C[(size_t)(rowb + r) * DIM + col] = v;
  }
}

// LN prologue: As[r] = bf16(LN(X[row]+R[row])*g+b) for 32 rows; optionally
// write fp32 LN result to x_out (bx==0 blocks).
__device__ __forceinline__ void ln_prologue(const float* __restrict__ X,
                                            const float* __restrict__ R,
                                            const float* __restrict__ g,
                                            const float* __restrict__ b,
                                            short* __restrict__ As, int by,
                                            float* x_out, int wave, int lane) {
  const int d0 = lane * 8;
  float gg[8], bb[8];
  {
    float4 g0 = *(const float4*)(g + d0);
    float4 g1 = *(const float4*)(g + d0 + 4);
    float4 b0 = *(const float4*)(b + d0);
    float4 b1 = *(const float4*)(b + d0 + 4);
    gg[0] = g0.x; gg[1] = g0.y; gg[2] = g0.z; gg[3] = g0.w;
    gg[4] = g1.x; gg[5] = g1.y; gg[6] = g1.z; gg[7] = g1.w;
    bb[0] = b0.x; bb[1] = b0.y; bb[2] = b0.z; bb[3] = b0.w;
    bb[4] = b1.x; bb[5] = b1.y; bb[6] = b1.z; bb[7] = b1.w;
  }
  for (int r = wave; r < 32; r += 4) {
    const int grow = by * 32 + r;
    const float* xp = X + (size_t)grow * DIM + d0;
    const float* rp = R + (size_t)grow * DIM + d0;
    float4 x0 = *(const float4*)xp;
    float4 x1 = *(const float4*)(xp + 4);
    float4 r0 = *(const float4*)rp;
    float4 r1 = *(const float4*)(rp + 4);
    float v[8] = {x0.x + r0.x, x0.y + r0.y, x0.z + r0.z, x0.w + r0.w,
                  x1.x + r1.x, x1.y + r1.y, x1.z + r1.z, x1.w + r1.w};
    float s = 0.f, sq = 0.f;
#pragma unroll
    for (int e = 0; e < 8; ++e) { s += v[e]; sq += v[e] * v[e]; }
#pragma unroll
    for (int o = 32; o > 0; o >>= 1) {
      s += __shfl_xor(s, o);
      sq += __shfl_xor(sq, o);
    }
    const float mean = s * (1.f / DIM);
    const float var = sq * (1.f / DIM) - mean * mean;
    const float rstd = rsqrtf(var + 1e-5f);
    float o8[8];
    short8 sv;
#pragma unroll
    for (int e = 0; e < 8; ++e) {
      o8[e] = (v[e] - mean) * rstd * gg[e] + bb[e];
      sv[e] = (short)f2bf(o8[e]);
    }
    *(short8*)(&As[r * LDS_W + d0]) = sv;
    if (x_out) {
      *(float4*)(x_out + (size_t)grow * DIM + d0) =
          make_float4(o8[0], o8[1], o8[2], o8[3]);
      *(float4*)(x_out + (size_t)grow * DIM + d0 + 4) =
          make_float4(o8[4], o8[5], o8[6], o8[7]);
    }
  }
}

// ---------------------------------------------------------------------------
// G1: combine partials (finish softmax) + ReLU  ->  GEMM with ca_t2l_w.
// ---------------------------------------------------------------------------
__global__ __launch_bounds__(256) void k_g1(
    const unsigned short* __restrict__ part_acc,
    const float* __restrict__ part_ms, const float* __restrict__ W,
    const float* __restrict__ bias, float* __restrict__ C) {
  __shared__ short As[32 * LDS_W];
  __shared__ short Ws[32 * LDS_W];
  const int tid = threadIdx.x;
  const int bx = blockIdx.x, by = blockIdx.y;
  const int wave = tid >> 6, lane = tid & 63;
  const int d0 = lane * 8;
  for (int r = wave; r < 32; r += 4) {
    const int i = by * 32 + r;
    const bool valid[3] = {i < S_Q - 1, true, i > 0};
    float mm[3], ss[3], M = -1e30f;
#pragma unroll
    for (int c = 0; c < 3; ++c) {
      if (valid[c]) {
        mm[c] = part_ms[((size_t)i * 3 + c) * 2 + 0];
        ss[c] = part_ms[((size_t)i * 3 + c) * 2 + 1];
        M = fmaxf(M, mm[c]);
      } else {
        mm[c] = -1e30f;
        ss[c] = 0.f;
      }
    }
    float den = 0.f, wg[3];
#pragma unroll
    for (int c = 0; c < 3; ++c) {
      wg[c] = valid[c] ? __expf(mm[c] - M) : 0.f;
      den += wg[c] * ss[c];
    }
    const float inv = 1.f / den;
    float o[8] = {0.f, 0.f, 0.f, 0.f, 0.f, 0.f, 0.f, 0.f};
#pragma unroll
    for (int c = 0; c < 3; ++c) {
      if (valid[c]) {
        const short8 pa =
            *(const short8*)(part_acc + ((size_t)i * 3 + c) * DIM + d0);
#pragma unroll
        for (int e = 0; e < 8; ++e) o[e] += wg[c] * bf2f(pa[e]);
      }
    }
    short8 sv;
#pragma unroll
    for (int e = 0; e < 8; ++e) sv[e] = (short)f2bf(fmaxf(o[e] * inv, 0.f));
    *(short8*)(&As[r * LDS_W + d0]) = sv;
  }
  stage_tile(W, Ws, bx, tid);
  __syncthreads();
  gemm_core<false>(As, Ws, bias, C, bx, by, wave, lane);
}

// ---------------------------------------------------------------------------
// G2/G5: LN(X+R) prologue (write x_out when bx==0) -> GEMM (ReLU epilogue).
// ---------------------------------------------------------------------------
__global__ __launch_bounds__(256) void k_gln(
    const float* __restrict__ X, const float* __restrict__ R,
    const float* __restrict__ g, const float* __restrict__ b,
    const float* __restrict__ W, const float* __restrict__ bias,
    float* __restrict__ C, float* __restrict__ x_out) {
  __shared__ short As[32 * LDS_W];
  __shared__ short Ws[32 * LDS_W];
  const int tid = threadIdx.x;
  const int bx = blockIdx.x, by = blockIdx.y;
  const int wave = tid >> 6, lane = tid & 63;
  ln_prologue(X, R, g, b, As, by, (bx == 0) ? x_out : nullptr, wave, lane);
  stage_tile(W, Ws, bx, tid);
  __syncthreads();
  gemm_core<true>(As, Ws, bias, C, bx, by, wave, lane);
}

// ---------------------------------------------------------------------------
// G3/G6: plain GEMM (A fp32 global), no relu.
// ---------------------------------------------------------------------------
__global__ __launch_bounds__(256) void k_gplain(
    const float* __restrict__ A, const float* __restrict__ W,
    const float* __restrict__ bias, float* __restrict__ C) {
  __shared__ short As[32 * LDS_W];
  __shared__ short Ws[32 * LDS_W];
  const int tid = threadIdx.x;
  const int bx = blockIdx.x, by = blockIdx.y;
  const int wave = tid >> 6, lane = tid & 63;
  stage_tile(A, As, by, tid);
  stage_tile(W, Ws, bx, tid);
  __syncthreads();
  gemm_core<false>(As, Ws, bias, C, bx, by, wave, lane);
}

// ---------------------------------------------------------------------------
// G4: x2 = LN(x+f) on a 40-row window (write own rows when bx==0), banded
// self-attention (+/-4) + ReLU -> GEMM with sa_conv_w.
// ---------------------------------------------------------------------------
__global__ __launch_bounds__(256) void k_g4(
    const float* __restrict__ X, const float* __restrict__ R,
    const float* __restrict__ g, const float* __restrict__ b,
    const float* __restrict__ W, const float* __restrict__ bias,
    float* __restrict__ C, float* __restrict__ x2_out) {
  __shared__ short Xw[40 * LDS_W];
  __shared__ short As[32 * LDS_W];
  __shared__ short Ws[32 * LDS_W];
  const int tid = threadIdx.x;
  const int bx = blockIdx.x, by = blockIdx.y;
  const int wave = tid >> 6, lane = tid & 63;
  const int d0 = lane * 8;
  const int wlo = (by * 32 - 4 > 0) ? by * 32 - 4 : 0;
  const int whi = (by * 32 + 35 < S_Q - 1) ? by * 32 + 35 : S_Q - 1;
  const int nw = whi - wlo + 1;

  {
    float gg[8], bb[8];
    float4 g0 = *(const float4*)(g + d0);
    float4 g1 = *(const float4*)(g + d0 + 4);
    float4 b0 = *(const float4*)(b + d0);
    float4 b1 = *(const float4*)(b + d0 + 4);
    gg[0] = g0.x; gg[1] = g0.y; gg[2] = g0.z; gg[3] = g0.w;
    gg[4] = g1.x; gg[5] = g1.y; gg[6] = g1.z; gg[7] = g1.w;
    bb[0] = b0.x; bb[1] = b0.y; bb[2] = b0.z; bb[3] = b0.w;
    bb[4] = b1.x; bb[5] = b1.y; bb[6] = b1.z; bb[7] = b1.w;
    for (int r = wave; r < nw; r += 4) {
      const int grow = wlo + r;
      const float* xp = X + (size_t)grow * DIM + d0;
      const float* rp = R + (size_t)grow * DIM + d0;
      float4 x0 = *(const float4*)xp;
      float4 x1 = *(const float4*)(xp + 4);
      float4 r0 = *(const float4*)rp;
      float4 r1 = *(const float4*)(rp + 4);
      float v[8] = {x0.x + r0.x, x0.y + r0.y, x0.z + r0.z, x0.w + r0.w,
                    x1.x + r1.x, x1.y + r1.y, x1.z + r1.z, x1.w + r1.w};
      float s = 0.f, sq = 0.f;
#pragma unroll
      for (int e = 0; e < 8; ++e) { s += v[e]; sq += v[e] * v[e]; }
#pragma unroll
      for (int o = 32; o > 0; o >>= 1) {
        s += __shfl_xor(s, o);
        sq += __shfl_xor(sq, o);
      }
      const float mean = s * (1.f / DIM);
      const float var = sq * (1.f / DIM) - mean * mean;
      const float rstd = rsqrtf(var + 1e-5f);
      float o8[8];
      short8 sv;
#pragma unroll
      for (int e = 0; e < 8; ++e) {
        o8[e] = (v[e] - mean) * rstd * gg[e] + bb[e];
        sv[e] = (short)f2bf(o8[e]);
      }
      *(short8*)(&Xw[r * LDS_W + d0]) = sv;
      if (bx == 0 && grow >= by * 32 && grow < by * 32 + 32) {
        *(float4*)(x2_out + (size_t)grow * DIM + d0) =
            make_float4(o8[0], o8[1], o8[2], o8[3]);
        *(float4*)(x2_out + (size_t)grow * DIM + d0 + 4) =
            make_float4(o8[4], o8[5], o8[6], o8[7]);
      }
    }
  }
  stage_tile(W, Ws, bx, tid);
  __syncthreads();

  for (int li = wave; li < 32; li += 4) {
    const int i = by * 32 + li;
    const int lq = i - wlo;
    float qv[8];
    {
      const short8 qs = *(const short8*)(&Xw[lq * LDS_W + d0]);
#pragma unroll
      for (int e = 0; e < 8; ++e) qv[e] = bf2f(qs[e]);
    }
    const int jlo = (i - 4 > 0) ? i - 4 : 0;
    const int jhi = (i + 4 < S_Q - 1) ? i + 4 : S_Q - 1;
    const int n = jhi - jlo + 1;
    float sc[9];
#pragma unroll
    for (int k = 0; k < 9; ++k) {
      if (k < n) {
        const int lk = jlo + k - wlo;
        const short8 ks = *(const short8*)(&Xw[lk * LDS_W + d0]);
        float dd = 0.f;
#pragma unroll
        for (int e = 0; e < 8; ++e) dd += qv[e] * bf2f(ks[e]);
        sc[k] = dd;
      } else {
        sc[k] = 0.f;
      }
    }
#pragma unroll
    for (int o = 32; o > 0; o >>= 1)
#pragma unroll
      for (int k = 0; k < 9; ++k) sc[k] += __shfl_xor(sc[k], o);
    float M = -1e30f;
#pragma unroll
    for (int k = 0; k < 9; ++k) {
      sc[k] *= SCALE_F;
      if (k < n) M = fmaxf(M, sc[k]);
    }
    float p[9], den = 0.f;
#pragma unroll
    for (int k = 0; k < 9; ++k) {
      p[k] = (k < n) ? __expf(sc[k] - M) : 0.f;
      den += p[k];
    }
    const float inv = 1.f / den;
    float o8[8] = {0.f, 0.f, 0.f, 0.f, 0.f, 0.f, 0.f, 0.f};
#pragma unroll
    for (int k = 0; k < 9; ++k) {
      if (k < n) {
        const int lk = jlo + k - wlo;
        const short8 ks = *(const short8*)(&Xw[lk * LDS_W + d0]);
#pragma unroll
        for (int e = 0; e < 8; ++e) o8[e] += p[k] * bf2f(ks[e]);
      }
    }
    short8 sv;
#pragma unroll
    for (int e = 0; e < 8; ++e) sv[e] = (short)f2bf(fmaxf(o8[e] * inv, 0.f));
    *(short8*)(&As[li * LDS_W + d0]) = sv;
  }
  __syncthreads();
  gemm_core<false>(As, Ws, bias, C, bx, by, wave, lane);
}

// ---------------------------------------------------------------------------
// Final: out = LN(y1 + f2).
// ---------------------------------------------------------------------------
__global__ __launch_bounds__(256) void k_addln(
    const float* __restrict__ X, const float* __restrict__ R,
    const float* __restrict__ g, const float* __restrict__ b,
    float* __restrict__ out) {
  const int row = blockIdx.x * 4 + (threadIdx.x >> 6);
  const int lane = threadIdx.x & 63;
  const int d = lane * 8;
  const float4* xp = (const float4*)(X + (size_t)row * DIM + d);
  const float4* rp = (const float4*)(R + (size_t)row * DIM + d);
  float4 x0 = xp[0], x1 = xp[1], r0 = rp[0], r1 = rp[1];
  float v[8] = {x0.x + r0.x, x0.y + r0.y, x0.z + r0.z, x0.w + r0.w,
                x1.x + r1.x, x1.y + r1.y, x1.z + r1.z, x1.w + r1.w};
  float s = 0.f, sq = 0.f;
#pragma unroll
  for (int e = 0; e < 8; ++e) { s += v[e]; sq += v[e] * v[e]; }
  s = wave_sum(s);
  sq = wave_sum(sq);
  const float mean = s * (1.f / DIM);
  const float var = sq * (1.f / DIM) - mean * mean;
  const float rstd = rsqrtf(var + 1e-5f);
  const float4* gp = (const float4*)(g + d);
  const float4* bp = (const float4*)(b + d);
  float4 g0 = gp[0], g1 = gp[1], bb0 = bp[0], bb1 = bp[1];
  float4 o0, o1;
  o0.x = (v[0] - mean) * rstd * g0.x + bb0.x;
  o0.y = (v[1] - mean) * rstd * g0.y + bb0.y;
  o0.z = (v[2] - mean) * rstd * g0.z + bb0.z;
  o0.w = (v[3] - mean) * rstd * g0.w + bb0.w;
  o1.x = (v[4] - mean) * rstd * g1.x + bb1.x;
  o1.y = (v[5] - mean) * rstd * g1.y + bb1.y;
  o1.z = (v[6] - mean) * rstd * g1.z + bb1.z;
  o1.w = (v[7] - mean) * rstd * g1.w + bb1.w;
  *(float4*)(out + (size_t)row * DIM + d) = o0;
  *(float4*)(out + (size_t)row * DIM + d + 4) = o1;
}

// ---------------------------------------------------------------------------
extern "C" void kernel_launch(void* const* d_in, const int* in_sizes, int n_in,
                              void* d_out, int out_size, void* d_ws, size_t ws_size,
                              hipStream_t stream) {
  const float* tgt       = (const float*)d_in[0];
  const float* memory    = (const float*)d_in[1];
  const float* pos       = (const float*)d_in[2];
  const float* qpos      = (const float*)d_in[3];
  // d_in[4] action_idx: analytically t/64, unused
  const float* ca_t2l_w  = (const float*)d_in[5];
  const float* ca_t2l_b  = (const float*)d_in[6];
  const float* ca_l1_w   = (const float*)d_in[7];
  const float* ca_l1_b   = (const float*)d_in[8];
  const float* ca_l2_w   = (const float*)d_in[9];
  const float* ca_l2_b   = (const float*)d_in[10];
  const float* ca_n2_g   = (const float*)d_in[11];
  const float* ca_n2_b   = (const float*)d_in[12];
  const float* ca_n3_g   = (const float*)d_in[13];
  const float* ca_n3_b   = (const float*)d_in[14];
  const float* sa_conv_w = (const float*)d_in[15];
  const float* sa_conv_b = (const float*)d_in[16];
  const float* sa_l1_w   = (const float*)d_in[17];
  const float* sa_l1_b   = (const float*)d_in[18];
  const float* sa_l2_w   = (const float*)d_in[19];
  const float* sa_l2_b   = (const float*)d_in[20];
  const float* sa_n1_g   = (const float*)d_in[21];
  const float* sa_n1_b   = (const float*)d_in[22];
  const float* sa_n2_g   = (const float*)d_in[23];
  const float* sa_n2_b   = (const float*)d_in[24];
  float* out = (float*)d_out;
  float* ws = (float*)d_ws;

  // workspace (floats). part region [0,396288) dead after G1; 1MB activation
  // buffers aliased by lifetime. Peak 4.73 MB.
  unsigned short* part_acc = (unsigned short*)ws;  // 512*3*512 bf16 = 1.5MB
  float* part_ms = ws + 393216;                    // 512*3*2
  float* t2 = ws + 396288;
  float* h  = ws + 658432;
  float* x  = ws + 920576;
  float* f  = ws + 0;        // after G1 (part dead)
  float* x2 = ws + 396288;   // after G2 (t2 dead)
  float* c  = ws + 658432;   // after G3 (h dead)
  float* y1 = ws + 0;        // after G4 (f dead)
  float* h2 = ws + 920576;   // after G4 (x dead)
  float* f2 = ws + 396288;   // after G5 (x2 dead)

  const dim3 gg(16, 16, 1);

  k_ca_partial<<<512, 256, 0, stream>>>(tgt, qpos, memory, pos, part_acc, part_ms);
  k_g1<<<gg, 256, 0, stream>>>(part_acc, part_ms, ca_t2l_w, ca_t2l_b, t2);
  k_gln<<<gg, 256, 0, stream>>>(tgt, t2, ca_n2_g, ca_n2_b, ca_l1_w, ca_l1_b, h, x);
  k_gplain<<<gg, 256, 0, stream>>>(h, ca_l2_w, ca_l2_b, f);
  k_g4<<<gg, 256, 0, stream>>>(x, f, ca_n3_g, ca_n3_b, sa_conv_w, sa_conv_b, c, x2);
  k_gln<<<gg, 256, 0, stream>>>(x2, c, sa_n1_g, sa_n1_b, sa_l1_w, sa_l1_b, h2, y1);
  k_gplain<<<gg, 256, 0, stream>>>(h2, sa_l2_w, sa_l2_b, f2);
  k_addln<<<128, 256, 0, stream>>>(f2, y1, sa_n2_g, sa_n2_b, out);
}